// Round 12
// baseline (334.349 us; speedup 1.0000x reference)
//
#include <hip/hip_runtime.h>
#include <hip/hip_bf16.h>
#include <math.h>

#define NN 50000
#define NE 400000
#define FIN 70
#define EDIM 4
#define HIDD 128
#define NHEAD 4
constexpr int ET = NE + NN;
constexpr int KP1 = 96;           // layer-1 K padded (70 -> 96)
constexpr int NP4 = 4 * KP1;      // interleaved agg row: [4][96] per node
constexpr int NFP = 72;           // nf bf16 row pitch
constexpr int SCB = (NN + 255) / 256;   // scan blocks = 196

constexpr size_t al4(size_t x){ return (x + 3) & ~size_t(3); }
// ws offsets in 4-byte words
constexpr size_t CNT_O   = 0;                          // int[NN]
constexpr size_t ZEND    = al4(CNT_O + NN);
constexpr size_t CSR_O   = ZEND;                       // int[NN+1]
constexpr size_t BSUM_O  = al4(CSR_O + NN + 1);        // int[256]
constexpr size_t BOFF_O  = al4(BSUM_O + 256);          // int[256] (unused now)
constexpr size_t EPK_O   = al4(BOFF_O + 256);          // int4[ET] {s,d,ea01,ea23}
constexpr size_t EXF1_O  = al4(EPK_O + (size_t)ET*4);  // float4[ET] exp scores L1
constexpr size_t RNK_O   = al4(EXF1_O + (size_t)ET*4); // int[NE] edge rank
constexpr size_t SS1_O   = al4(RNK_O + ET);            // f32[NN*4]
constexpr size_t SD1_O   = al4(SS1_O + (size_t)NN*4);
constexpr size_t SS2_O   = al4(SD1_O + (size_t)NN*4);  // f32[NN]
constexpr size_t SD2_O   = al4(SS2_O + NN);
constexpr size_t CST_O   = al4(SD2_O + NN);            // f32[2048]
constexpr size_t W1T_O   = al4(CST_O + 2048);          // bf16[12][128][32] panel-major
constexpr size_t W2T_O   = al4(W1T_O + 4*128*KP1/2);   // bf16[16][128][32] panel-major
constexpr size_t NFB_O   = al4(W2T_O + 128*512/2);     // bf16[NN][72]
constexpr size_t AGG_O   = al4(NFB_O + (size_t)NN*NFP/2);   // bf16[NN][4][96] interleaved
constexpr size_t XS2_O   = al4(AGG_O + (size_t)NN*NP4/2);   // bf16[NN][128]

// const-block sub-offsets (words, within CST)
constexpr int VS1 = 0;    // [70][4]
constexpr int VD1 = 320;  // [70][4]
constexpr int VE1 = 640;  // [4][4]
constexpr int VE2 = 656;  // [4]
constexpr int VS2 = 704;  // [512]
constexpr int VD2 = 1216; // [512]

// merged-kernel block ranges
constexpr int TW_BLK = (12*128*32 + 16*128*32) / 256;  // 448 transpose blocks
constexpr int CN_BLK = (NN + 3) / 4;                   // 12500 cnfs1 blocks
constexpr int DG_BLK = (NE + 255) / 256;               // 1563 deg blocks

typedef short s8v __attribute__((ext_vector_type(8)));
typedef float f4v __attribute__((ext_vector_type(4)));

__device__ __forceinline__ unsigned short f2b(float v){
  __hip_bfloat16 b = __float2bfloat16(v);
  return *(unsigned short*)&b;
}
__device__ __forceinline__ float b2f(unsigned u_lo16){
  return __uint_as_float(u_lo16 << 16);
}
__device__ __forceinline__ unsigned pk2(float lo, float hi){
  return (unsigned)f2b(lo) | ((unsigned)f2b(hi) << 16);
}
__device__ __forceinline__ float lrelu(float x){ return x > 0.f ? x : 0.2f * x; }

// erf via A&S 7.1.26 (|err|<1.5e-7), one fast v_exp — avoids libm erff
__device__ __forceinline__ float gelu_fast(float x){
  float z = x * 0.70710678118654752440f;
  float a = fabsf(z);
  float t = 1.f / (1.f + 0.3275911f * a);
  float p = ((((1.061405429f*t - 1.453152027f)*t + 1.421413741f)*t
              - 0.284496736f)*t + 0.254829592f)*t;
  float erfv = 1.f - p * __expf(-a * a);
  erfv = copysignf(erfv, z);
  return 0.5f * x * (1.f + erfv);
}

// ---- MERGED: weight transpose + tiny pre-reductions + cnt zero --------------
__global__ void k_ptw(const float* __restrict__ W1, const float* __restrict__ as1,
                      const float* __restrict__ ad1, const float* __restrict__ We1,
                      const float* __restrict__ ae1, const float* __restrict__ W2,
                      const float* __restrict__ as2, const float* __restrict__ ad2,
                      const float* __restrict__ We2, const float* __restrict__ ae2,
                      float* __restrict__ C, unsigned short* __restrict__ W1p,
                      unsigned short* __restrict__ W2p, int* __restrict__ cnt){
  int bid = blockIdx.x, tid = threadIdx.x;
  if (bid < TW_BLK){
    int i = bid * 256 + tid;
    if (i < 12*128*32){
      int kk = i & 31, r = (i >> 5) & 127, ph = i >> 12;
      int h = ph / 3, kf = ph - 3*h;
      int kg = kf*32 + kk;
      float v = (kg < FIN) ? W1[kg*512 + h*128 + r] : 0.f;
      W1p[i] = f2b(v);
    } else {
      int j = i - 12*128*32;
      int kk = j & 31, r = (j >> 5) & 127, p = j >> 12;
      W2p[j] = f2b(W2[(p*32 + kk)*128 + r]);
    }
    return;
  }
  if (bid == TW_BLK){
    for (int t = tid; t < 512; t += 256){
      if (t < 280){
        int k = t >> 2, h = t & 3;
        float s = 0.f, d = 0.f;
        for (int dd = 0; dd < 128; ++dd){
          float w = W1[k*512 + h*128 + dd];
          s += w * as1[h*128 + dd];
          d += w * ad1[h*128 + dd];
        }
        C[VS1 + t] = s; C[VD1 + t] = d;
      }
      if (t < 16){
        int k = t >> 2, h = t & 3;
        float s = 0.f;
        for (int dd = 0; dd < 128; ++dd) s += We1[k*512 + h*128 + dd] * ae1[h*128 + dd];
        C[VE1 + t] = s;
      }
      if (t < 4){
        float s = 0.f;
        for (int dd = 0; dd < 128; ++dd) s += We2[t*128 + dd] * ae2[dd];
        C[VE2 + t] = s;
      }
      {
        float s = 0.f, d = 0.f;
        for (int dd = 0; dd < 128; ++dd){
          float w = W2[t*128 + dd];
          s += w * as2[dd];
          d += w * ad2[dd];
        }
        C[VS2 + t] = s; C[VD2 + t] = d;
      }
    }
    return;
  }
  int i = (bid - TW_BLK - 1) * 256 + tid;
  if (i < NN) cnt[i] = 0;
}

// ---- MERGED: nf -> bf16 + layer1 attn scalars  ||  degree histogram + rank --
__global__ __launch_bounds__(256) void k_cnfs1(const float* __restrict__ nf,
    const float* __restrict__ C, unsigned short* __restrict__ nfb,
    float* __restrict__ ss1, float* __restrict__ sd1,
    const int* __restrict__ ei, int* __restrict__ cnt, int* __restrict__ rnk){
  int bid = blockIdx.x;
  if (bid >= CN_BLK){
    int e = (bid - CN_BLK) * 256 + threadIdx.x;
    if (e < NE) rnk[e] = atomicAdd(&cnt[ei[NE + e]], 1);
    return;
  }
  int lane = threadIdx.x & 63, w = threadIdx.x >> 6;
  int n = bid * 4 + w;
  if (n >= NN) return;
  int c0 = lane * 2;
  bool act = lane < 35;                 // cols 0..69
  float v0 = 0.f, v1 = 0.f;
  if (act){
    v0 = nf[(size_t)n * FIN + c0];
    v1 = nf[(size_t)n * FIN + c0 + 1];
  }
  if (lane < 36) *(unsigned*)&nfb[(size_t)n * NFP + c0] = act ? pk2(v0, v1) : 0u;
  float sh[4] = {0,0,0,0}, dh[4] = {0,0,0,0};
  if (act){
    float4 cs0 = *(const float4*)&C[VS1 + c0*4];
    float4 cs1 = *(const float4*)&C[VS1 + (c0+1)*4];
    float4 cd0 = *(const float4*)&C[VD1 + c0*4];
    float4 cd1 = *(const float4*)&C[VD1 + (c0+1)*4];
    sh[0] = v0*cs0.x + v1*cs1.x; sh[1] = v0*cs0.y + v1*cs1.y;
    sh[2] = v0*cs0.z + v1*cs1.z; sh[3] = v0*cs0.w + v1*cs1.w;
    dh[0] = v0*cd0.x + v1*cd1.x; dh[1] = v0*cd0.y + v1*cd1.y;
    dh[2] = v0*cd0.z + v1*cd1.z; dh[3] = v0*cd0.w + v1*cd1.w;
  }
  #pragma unroll
  for (int o = 32; o; o >>= 1){
    #pragma unroll
    for (int h = 0; h < 4; ++h){
      sh[h] += __shfl_xor(sh[h], o);
      dh[h] += __shfl_xor(dh[h], o);
    }
  }
  if (lane == 0){
    *(float4*)&ss1[(size_t)n*4] = make_float4(sh[0], sh[1], sh[2], sh[3]);
    *(float4*)&sd1[(size_t)n*4] = make_float4(dh[0], dh[1], dh[2], dh[3]);
  }
}

// ---- CSR build: scan1 (block sums) + merged scan2/3 -------------------------
__global__ void k_scan1(const int* __restrict__ cnt, int* __restrict__ bsum){
  __shared__ int ws[4];
  int t = threadIdx.x, lane = t & 63, w = t >> 6;
  int i = blockIdx.x * 256 + t;
  int v = (i < NN) ? cnt[i] + 1 : 0;
  for (int o = 32; o; o >>= 1) v += __shfl_down(v, o);
  if (lane == 0) ws[w] = v;
  __syncthreads();
  if (t == 0) bsum[blockIdx.x] = ws[0] + ws[1] + ws[2] + ws[3];
}

__global__ void k_scan3(const int* __restrict__ cnt, const int* __restrict__ bsum,
                        int* __restrict__ csr){
  __shared__ int ws[4];
  __shared__ int blockoff;
  int t = threadIdx.x, lane = t & 63, w = t >> 6;
  // phase A: exclusive scan of bsum, keep entry blockIdx.x
  {
    int v = (t < SCB) ? bsum[t] : 0;
    int x = v;
    #pragma unroll
    for (int o = 1; o < 64; o <<= 1){ int u = __shfl_up(x, o); if (lane >= o) x += u; }
    if (lane == 63) ws[w] = x;
    __syncthreads();
    if (w == 0 && lane < 4){
      int y = ws[lane];
      #pragma unroll
      for (int o = 1; o < 4; o <<= 1){ int u = __shfl_up(y, o); if (lane >= o) y += u; }
      ws[lane] = y;
    }
    __syncthreads();
    int incl = x + (w > 0 ? ws[w - 1] : 0);
    if (t == blockIdx.x) blockoff = incl - v;
  }
  __syncthreads();                      // ws reads done; safe to reuse
  // phase B: per-element scan of this block's (cnt+1)
  int i = blockIdx.x * 256 + t;
  int v = (i < NN) ? cnt[i] + 1 : 0;
  int x = v;
  #pragma unroll
  for (int o = 1; o < 64; o <<= 1){ int u = __shfl_up(x, o); if (lane >= o) x += u; }
  if (lane == 63) ws[w] = x;
  __syncthreads();
  if (w == 0 && lane < 4){
    int y = ws[lane];
    #pragma unroll
    for (int o = 1; o < 4; o <<= 1){ int u = __shfl_up(y, o); if (lane >= o) y += u; }
    ws[lane] = y;
  }
  __syncthreads();
  if (i < NN) csr[i + 1] = blockoff + (w > 0 ? ws[w - 1] : 0) + x;
  if (i == 0) csr[0] = 0;
}

// ---- fill CSR slots + FUSED layer-1 alpha (edge-parallel, ONCE per edge) ----
__global__ void k_fill(const int* __restrict__ ei, const float* __restrict__ ea,
                       const int* __restrict__ csr, const int* __restrict__ rnk,
                       int4* __restrict__ epk, const float* __restrict__ ss1,
                       const float* __restrict__ sd1, const float* __restrict__ C,
                       float4* __restrict__ exf){
  int e = blockIdx.x * 256 + threadIdx.x;
  if (e >= NE) return;
  int s = ei[e], d = ei[NE + e];
  int p = csr[d] + rnk[e];
  float4 a = *(const float4*)&ea[(size_t)e * 4];
  epk[p] = make_int4(s, d, (int)pk2(a.x, a.y), (int)pk2(a.z, a.w));
  float4 ssv = *(const float4*)&ss1[(size_t)s * 4];
  float4 sdv = *(const float4*)&sd1[(size_t)d * 4];
  float e0 = __expf(lrelu(ssv.x + sdv.x + a.x*C[VE1+0] + a.y*C[VE1+4] + a.z*C[VE1+8]  + a.w*C[VE1+12]));
  float e1 = __expf(lrelu(ssv.y + sdv.y + a.x*C[VE1+1] + a.y*C[VE1+5] + a.z*C[VE1+9]  + a.w*C[VE1+13]));
  float e2 = __expf(lrelu(ssv.z + sdv.z + a.x*C[VE1+2] + a.y*C[VE1+6] + a.z*C[VE1+10] + a.w*C[VE1+14]));
  float e3 = __expf(lrelu(ssv.w + sdv.w + a.x*C[VE1+3] + a.y*C[VE1+7] + a.z*C[VE1+11] + a.w*C[VE1+15]));
  exf[p] = make_float4(e0, e1, e2, e3);
}

// ---- FUSED two-stage GEMM: 2x2 wave tiling, B read ONCE per block -----------
// Round-12: all 12 stage-1 A-fragments per row hoisted to the prologue (one
// contiguous 768B run per row thanks to r11's interleaved layout) — the
// stage-1 inner loop is now pure B-load + MFMA. Otherwise r6 config.
__global__ __launch_bounds__(256, 4) void k_gemm12(
    const unsigned short* __restrict__ agg, const unsigned short* __restrict__ W1p,
    const unsigned short* __restrict__ W2p, const float* __restrict__ b1,
    const float* __restrict__ Cv, unsigned short* __restrict__ xs2b,
    float* __restrict__ ss2, float* __restrict__ sd2){
  __shared__ unsigned short xt[32 * 516];   // 33.0 KB
  __shared__ float ssp[32][4], sdp[32][4];
  int tid = threadIdx.x, lane = tid & 63, wn = tid >> 6;  // wn 0..3: 32-col strip
  int m15 = lane & 15, rq = lane >> 4;
  int r0 = blockIdx.x * 32;
  int gr0 = r0 + m15;      if (gr0 >= NN) gr0 = NN - 1;
  int gr1 = r0 + 16 + m15; if (gr1 >= NN) gr1 = NN - 1;
  float s2a0 = 0.f, s2d0 = 0.f, s2a1 = 0.f, s2d1 = 0.f;
  const int bfo = (wn * 32 + m15) * 32 + rq * 8;   // +ni*512 per 16-col frag
  const unsigned short* A0 = agg + (size_t)gr0 * NP4 + rq * 8;
  const unsigned short* A1 = agg + (size_t)gr1 * NP4 + rq * 8;

  // prologue: hoist ALL stage-1 A fragments (independent, contiguous streams)
  s8v af0[4][3], af1[4][3];
  #pragma unroll
  for (int h = 0; h < 4; ++h)
    #pragma unroll
    for (int kf = 0; kf < 3; ++kf){
      af0[h][kf] = *(const s8v*)(A0 + h * KP1 + kf * 32);
      af1[h][kf] = *(const s8v*)(A1 + h * KP1 + kf * 32);
    }

  // ---------------- stage 1: 4 heads x 3 k-panels ----------------
  #pragma unroll
  for (int h = 0; h < 4; ++h){
    f4v acc[2][2] = {};
    const unsigned short* Bh = W1p + h * 3 * 4096 + bfo;
    #pragma unroll
    for (int kf = 0; kf < 3; ++kf){
      #pragma unroll
      for (int ni = 0; ni < 2; ++ni){
        s8v bf = *(const s8v*)(Bh + kf * 4096 + ni * 512);
        acc[0][ni] = __builtin_amdgcn_mfma_f32_16x16x32_bf16(bf, af0[h][kf], acc[0][ni], 0, 0, 0);
        acc[1][ni] = __builtin_amdgcn_mfma_f32_16x16x32_bf16(bf, af1[h][kf], acc[1][ni], 0, 0, 0);
      }
    }
    // head epilogue: gelu + xt write + ss2/sd2 register accumulation (2 rows)
    #pragma unroll
    for (int m = 0; m < 2; ++m){
      #pragma unroll
      for (int ni = 0; ni < 2; ++ni){
        int cb = h * 128 + wn * 32 + ni * 16 + rq * 4;
        float4 bv = *(const float4*)&b1[cb];
        float v0 = gelu_fast(acc[m][ni][0] + bv.x);
        float v1 = gelu_fast(acc[m][ni][1] + bv.y);
        float v2 = gelu_fast(acc[m][ni][2] + bv.z);
        float v3 = gelu_fast(acc[m][ni][3] + bv.w);
        float4 cs = *(const float4*)&Cv[VS2 + cb];
        float4 cd = *(const float4*)&Cv[VD2 + cb];
        float pa = v0*cs.x + v1*cs.y + v2*cs.z + v3*cs.w;
        float pd = v0*cd.x + v1*cd.y + v2*cd.z + v3*cd.w;
        if (m == 0){ s2a0 += pa; s2d0 += pd; } else { s2a1 += pa; s2d1 += pd; }
        *(uint2*)&xt[(m * 16 + m15) * 516 + cb] = make_uint2(pk2(v0, v1), pk2(v2, v3));
      }
    }
  }
  // ss2/sd2: reduce over rq lanes, park per-wave partials in tiny LDS
  s2a0 += __shfl_xor(s2a0, 16); s2a0 += __shfl_xor(s2a0, 32);
  s2d0 += __shfl_xor(s2d0, 16); s2d0 += __shfl_xor(s2d0, 32);
  s2a1 += __shfl_xor(s2a1, 16); s2a1 += __shfl_xor(s2a1, 32);
  s2d1 += __shfl_xor(s2d1, 16); s2d1 += __shfl_xor(s2d1, 32);
  if (rq == 0){
    ssp[m15][wn] = s2a0;      sdp[m15][wn] = s2d0;
    ssp[16 + m15][wn] = s2a1; sdp[16 + m15][wn] = s2d1;
  }

  __syncthreads();                          // the ONLY barrier

  if (tid < 32 && r0 + tid < NN){
    ss2[r0 + tid] = (ssp[tid][0] + ssp[tid][1]) + (ssp[tid][2] + ssp[tid][3]);
    sd2[r0 + tid] = (sdp[tid][0] + sdp[tid][1]) + (sdp[tid][2] + sdp[tid][3]);
  }

  // ---------------- stage 2: 16 k-panels ----------------
  f4v acc2[2][2] = {};
  #pragma unroll
  for (int p = 0; p < 16; ++p){
    s8v x0 = *(const s8v*)&xt[m15 * 516 + p * 32 + rq * 8];
    s8v x1 = *(const s8v*)&xt[(16 + m15) * 516 + p * 32 + rq * 8];
    #pragma unroll
    for (int ni = 0; ni < 2; ++ni){
      s8v bf = *(const s8v*)(W2p + p * 4096 + bfo + ni * 512);
      acc2[0][ni] = __builtin_amdgcn_mfma_f32_16x16x32_bf16(bf, x0, acc2[0][ni], 0, 0, 0);
      acc2[1][ni] = __builtin_amdgcn_mfma_f32_16x16x32_bf16(bf, x1, acc2[1][ni], 0, 0, 0);
    }
  }
  #pragma unroll
  for (int m = 0; m < 2; ++m){
    int grow = r0 + m * 16 + m15;
    if (grow < NN){
      #pragma unroll
      for (int ni = 0; ni < 2; ++ni){
        int gc = wn * 32 + ni * 16 + rq * 4;
        *(uint2*)&xs2b[(size_t)grow * 128 + gc] =
            make_uint2(pk2(acc2[m][ni][0], acc2[m][ni][1]),
                       pk2(acc2[m][ni][2], acc2[m][ni][3]));
      }
    }
  }
}

// ---- layer1 aggregation (reads exf) + FUSED self-loop, 4-wide edge unroll ---
__global__ __launch_bounds__(256) void k_aggnf(const int* __restrict__ csr,
    int4* __restrict__ epk, const float4* __restrict__ exf,
    const unsigned short* __restrict__ nfb, const float* __restrict__ ss1,
    const float* __restrict__ sd1, const float* __restrict__ Cv,
    unsigned short* __restrict__ agg){
  int lane = threadIdx.x & 63, w = threadIdx.x >> 6;
  int n = blockIdx.x * 4 + w;
  if (n >= NN) return;
  int off = __builtin_amdgcn_readfirstlane(csr[n]);
  int end = __builtin_amdgcn_readfirstlane(csr[n + 1]);
  int endr = end - 1;                   // real edges in [off, endr)
  int col = lane * 2;
  bool act = lane < 36;
  float d0=0,d1=0,d2=0,d3=0;
  float a00=0,a01=0,a10=0,a11=0,a20=0,a21=0,a30=0,a31=0;
  float t0=0,t1=0,t2=0,t3=0;            // attr sums for self-loop mean
  int p = off;
  for (; p + 4 <= endr; p += 4){
    int4 q0 = epk[p], q1 = epk[p+1], q2 = epk[p+2], q3 = epk[p+3];
    float4 e0 = exf[p], e1 = exf[p+1], e2 = exf[p+2], e3 = exf[p+3];
    unsigned u0 = 0, u1 = 0, u2 = 0, u3 = 0;
    if (act){
      u0 = *(const unsigned*)&nfb[(size_t)q0.x * NFP + col];
      u1 = *(const unsigned*)&nfb[(size_t)q1.x * NFP + col];
      u2 = *(const unsigned*)&nfb[(size_t)q2.x * NFP + col];
      u3 = *(const unsigned*)&nfb[(size_t)q3.x * NFP + col];
    }
    t0 += (b2f((unsigned)q0.z & 0xffffu) + b2f((unsigned)q1.z & 0xffffu))
        + (b2f((unsigned)q2.z & 0xffffu) + b2f((unsigned)q3.z & 0xffffu));
    t1 += (b2f((unsigned)q0.z >> 16) + b2f((unsigned)q1.z >> 16))
        + (b2f((unsigned)q2.z >> 16) + b2f((unsigned)q3.z >> 16));
    t2 += (b2f((unsigned)q0.w & 0xffffu) + b2f((unsigned)q1.w & 0xffffu))
        + (b2f((unsigned)q2.w & 0xffffu) + b2f((unsigned)q3.w & 0xffffu));
    t3 += (b2f((unsigned)q0.w >> 16) + b2f((unsigned)q1.w >> 16))
        + (b2f((unsigned)q2.w >> 16) + b2f((unsigned)q3.w >> 16));
    d0 += (e0.x + e1.x) + (e2.x + e3.x);
    d1 += (e0.y + e1.y) + (e2.y + e3.y);
    d2 += (e0.z + e1.z) + (e2.z + e3.z);
    d3 += (e0.w + e1.w) + (e2.w + e3.w);
    float v00 = b2f(u0 & 0xffffu), v01 = b2f(u0 >> 16);
    float v10 = b2f(u1 & 0xffffu), v11 = b2f(u1 >> 16);
    float v20 = b2f(u2 & 0xffffu), v21 = b2f(u2 >> 16);
    float v30 = b2f(u3 & 0xffffu), v31 = b2f(u3 >> 16);
    a00 += (e0.x*v00 + e1.x*v10) + (e2.x*v20 + e3.x*v30);
    a01 += (e0.x*v01 + e1.x*v11) + (e2.x*v21 + e3.x*v31);
    a10 += (e0.y*v00 + e1.y*v10) + (e2.y*v20 + e3.y*v30);
    a11 += (e0.y*v01 + e1.y*v11) + (e2.y*v21 + e3.y*v31);
    a20 += (e0.z*v00 + e1.z*v10) + (e2.z*v20 + e3.z*v30);
    a21 += (e0.z*v01 + e1.z*v11) + (e2.z*v21 + e3.z*v31);
    a30 += (e0.w*v00 + e1.w*v10) + (e2.w*v20 + e3.w*v30);
    a31 += (e0.w*v01 + e1.w*v11) + (e2.w*v21 + e3.w*v31);
  }
  for (; p + 2 <= endr; p += 2){
    int4 q0 = epk[p], q1 = epk[p+1];
    float4 e0 = exf[p], e1 = exf[p+1];
    unsigned u0 = 0, u1 = 0;
    if (act){
      u0 = *(const unsigned*)&nfb[(size_t)q0.x * NFP + col];
      u1 = *(const unsigned*)&nfb[(size_t)q1.x * NFP + col];
    }
    t0 += b2f((unsigned)q0.z & 0xffffu) + b2f((unsigned)q1.z & 0xffffu);
    t1 += b2f((unsigned)q0.z >> 16)     + b2f((unsigned)q1.z >> 16);
    t2 += b2f((unsigned)q0.w & 0xffffu) + b2f((unsigned)q1.w & 0xffffu);
    t3 += b2f((unsigned)q0.w >> 16)     + b2f((unsigned)q1.w >> 16);
    d0 += e0.x + e1.x; d1 += e0.y + e1.y; d2 += e0.z + e1.z; d3 += e0.w + e1.w;
    float v00 = b2f(u0 & 0xffffu), v01 = b2f(u0 >> 16);
    float v10 = b2f(u1 & 0xffffu), v11 = b2f(u1 >> 16);
    a00 += e0.x*v00 + e1.x*v10; a01 += e0.x*v01 + e1.x*v11;
    a10 += e0.y*v00 + e1.y*v10; a11 += e0.y*v01 + e1.y*v11;
    a20 += e0.z*v00 + e1.z*v10; a21 += e0.z*v01 + e1.z*v11;
    a30 += e0.w*v00 + e1.w*v10; a31 += e0.w*v01 + e1.w*v11;
  }
  if (p < endr){
    int4 q0 = epk[p];
    float4 e0 = exf[p];
    unsigned u0 = 0;
    if (act) u0 = *(const unsigned*)&nfb[(size_t)q0.x * NFP + col];
    t0 += b2f((unsigned)q0.z & 0xffffu); t1 += b2f((unsigned)q0.z >> 16);
    t2 += b2f((unsigned)q0.w & 0xffffu); t3 += b2f((unsigned)q0.w >> 16);
    d0 += e0.x; d1 += e0.y; d2 += e0.z; d3 += e0.w;
    float v00 = b2f(u0 & 0xffffu), v01 = b2f(u0 >> 16);
    a00 += e0.x*v00; a01 += e0.x*v01;
    a10 += e0.y*v00; a11 += e0.y*v01;
    a20 += e0.z*v00; a21 += e0.z*v01;
    a30 += e0.w*v00; a31 += e0.w*v01;
  }
  // ---- self loop: mean attrs (bf16-rounded like k_fill), alpha, contribution
  int deg = endr - off;
  float inv = 1.f / (float)(deg > 1 ? deg : 1);
  float m0 = t0*inv, m1 = t1*inv, m2 = t2*inv, m3 = t3*inv;
  if (lane == 0) epk[endr] = make_int4(n, n, (int)pk2(m0, m1), (int)pk2(m2, m3));
  float4 ssv = *(const float4*)&ss1[(size_t)n * 4];
  float4 sdn = *(const float4*)&sd1[(size_t)n * 4];
  float e0 = __expf(lrelu(ssv.x + sdn.x + m0*Cv[VE1+0] + m1*Cv[VE1+4] + m2*Cv[VE1+8]  + m3*Cv[VE1+12]));
  float e1 = __expf(lrelu(ssv.y + sdn.y + m0*Cv[VE1+1] + m1*Cv[VE1+5] + m2*Cv[VE1+9]  + m3*Cv[VE1+13]));
  float e2 = __expf(lrelu(ssv.z + sdn.z + m0*Cv[VE1+2] + m1*Cv[VE1+6] + m2*Cv[VE1+10] + m3*Cv[VE1+14]));
  float e3 = __expf(lrelu(ssv.w + sdn.w + m0*Cv[VE1+3] + m1*Cv[VE1+7] + m2*Cv[VE1+11] + m3*Cv[VE1+15]));
  {
    unsigned us = act ? *(const unsigned*)&nfb[(size_t)n * NFP + col] : 0u;
    float v0 = b2f(us & 0xffffu), v1 = b2f(us >> 16);
    d0 += e0; d1 += e1; d2 += e2; d3 += e3;
    a00 += e0*v0; a01 += e0*v1;
    a10 += e1*v0; a11 += e1*v1;
    a20 += e2*v0; a21 += e2*v1;
    a30 += e3*v0; a31 += e3*v1;
  }
  float i0 = 1.f/(d0+1e-16f), i1 = 1.f/(d1+1e-16f);
  float i2 = 1.f/(d2+1e-16f), i3 = 1.f/(d3+1e-16f);
  size_t base = (size_t)n * NP4 + col;
  if (act){
    *(unsigned*)&agg[base]           = pk2(a00*i0, a01*i0);
    *(unsigned*)&agg[base +   KP1]   = pk2(a10*i1, a11*i1);
    *(unsigned*)&agg[base + 2*KP1]   = pk2(a20*i2, a21*i2);
    *(unsigned*)&agg[base + 3*KP1]   = pk2(a30*i3, a31*i3);
  } else if (lane < 48){                // zero cols 72..95
    *(unsigned*)&agg[base]           = 0u;
    *(unsigned*)&agg[base +   KP1]   = 0u;
    *(unsigned*)&agg[base + 2*KP1]   = 0u;
    *(unsigned*)&agg[base + 3*KP1]   = 0u;
  }
}

// ---- layer2 aggregation + FUSED alpha + GELU + LN + projections -------------
__global__ __launch_bounds__(256) void k_agg2(
    const int* __restrict__ csr, const int4* __restrict__ epk,
    const float* __restrict__ ss2, const float* __restrict__ sd2,
    const float* __restrict__ Cv, const unsigned short* __restrict__ xs2b,
    const float* __restrict__ b2, const float* __restrict__ lng,
    const float* __restrict__ lnb, const float* __restrict__ pw,
    const float* __restrict__ pb, const float* __restrict__ dwm,
    const float* __restrict__ dbv, float* __restrict__ out){
  int lane = threadIdx.x & 63, w = threadIdx.x >> 6;
  int n = blockIdx.x * 4 + w;
  if (n >= NN) return;
  int off = __builtin_amdgcn_readfirstlane(csr[n]);
  int end = __builtin_amdgcn_readfirstlane(csr[n + 1]);
  float sd2n = sd2[n];
  float cv0 = Cv[VE2], cv1 = Cv[VE2+1], cv2 = Cv[VE2+2], cv3 = Cv[VE2+3];
  int c0 = lane * 2;
  float acc0 = 0.f, acc1 = 0.f, den = 0.f;
  int p = off;
  for (; p + 4 <= end; p += 4){
    int4 p0 = epk[p], p1 = epk[p+1], p2 = epk[p+2], p3 = epk[p+3];
    int s0 = p0.x, s1 = p1.x, s2 = p2.x, s3 = p3.x;
    float sv0 = ss2[s0], sv1 = ss2[s1], sv2 = ss2[s2], sv3 = ss2[s3];
    unsigned u0 = *(const unsigned*)&xs2b[(size_t)s0 * 128 + c0];
    unsigned u1 = *(const unsigned*)&xs2b[(size_t)s1 * 128 + c0];
    unsigned u2 = *(const unsigned*)&xs2b[(size_t)s2 * 128 + c0];
    unsigned u3 = *(const unsigned*)&xs2b[(size_t)s3 * 128 + c0];
    float e0 = __expf(lrelu(sv0 + sd2n
             + b2f((unsigned)p0.z & 0xffffu)*cv0 + b2f((unsigned)p0.z >> 16)*cv1
             + b2f((unsigned)p0.w & 0xffffu)*cv2 + b2f((unsigned)p0.w >> 16)*cv3));
    float e1 = __expf(lrelu(sv1 + sd2n
             + b2f((unsigned)p1.z & 0xffffu)*cv0 + b2f((unsigned)p1.z >> 16)*cv1
             + b2f((unsigned)p1.w & 0xffffu)*cv2 + b2f((unsigned)p1.w >> 16)*cv3));
    float e2 = __expf(lrelu(sv2 + sd2n
             + b2f((unsigned)p2.z & 0xffffu)*cv0 + b2f((unsigned)p2.z >> 16)*cv1
             + b2f((unsigned)p2.w & 0xffffu)*cv2 + b2f((unsigned)p2.w >> 16)*cv3));
    float e3 = __expf(lrelu(sv3 + sd2n
             + b2f((unsigned)p3.z & 0xffffu)*cv0 + b2f((unsigned)p3.z >> 16)*cv1
             + b2f((unsigned)p3.w & 0xffffu)*cv2 + b2f((unsigned)p3.w >> 16)*cv3));
    den += (e0 + e1) + (e2 + e3);
    acc0 += (e0*b2f(u0 & 0xffffu) + e1*b2f(u1 & 0xffffu))
          + (e2*b2f(u2 & 0xffffu) + e3*b2f(u3 & 0xffffu));
    acc1 += (e0*b2f(u0 >> 16) + e1*b2f(u1 >> 16))
          + (e2*b2f(u2 >> 16) + e3*b2f(u3 >> 16));
  }
  for (; p + 2 <= end; p += 2){
    int4 p0 = epk[p], p1 = epk[p+1];
    int s0 = p0.x, s1 = p1.x;
    float sv0 = ss2[s0], sv1 = ss2[s1];
    unsigned u0 = *(const unsigned*)&xs2b[(size_t)s0 * 128 + c0];
    unsigned u1 = *(const unsigned*)&xs2b[(size_t)s1 * 128 + c0];
    float e0 = __expf(lrelu(sv0 + sd2n
             + b2f((unsigned)p0.z & 0xffffu)*cv0 + b2f((unsigned)p0.z >> 16)*cv1
             + b2f((unsigned)p0.w & 0xffffu)*cv2 + b2f((unsigned)p0.w >> 16)*cv3));
    float e1 = __expf(lrelu(sv1 + sd2n
             + b2f((unsigned)p1.z & 0xffffu)*cv0 + b2f((unsigned)p1.z >> 16)*cv1
             + b2f((unsigned)p1.w & 0xffffu)*cv2 + b2f((unsigned)p1.w >> 16)*cv3));
    den += e0 + e1;
    acc0 += e0*b2f(u0 & 0xffffu) + e1*b2f(u1 & 0xffffu);
    acc1 += e0*b2f(u0 >> 16) + e1*b2f(u1 >> 16);
  }
  if (p < end){
    int4 p0 = epk[p];
    int s0 = p0.x;
    float sv0 = ss2[s0];
    unsigned u0 = *(const unsigned*)&xs2b[(size_t)s0 * 128 + c0];
    float e0 = __expf(lrelu(sv0 + sd2n
             + b2f((unsigned)p0.z & 0xffffu)*cv0 + b2f((unsigned)p0.z >> 16)*cv1
             + b2f((unsigned)p0.w & 0xffffu)*cv2 + b2f((unsigned)p0.w >> 16)*cv3));
    den += e0;
    acc0 += e0*b2f(u0 & 0xffffu);
    acc1 += e0*b2f(u0 >> 16);
  }
  float invd = 1.f / (den + 1e-16f);
  float g0 = gelu_fast(acc0 * invd + b2[c0]);
  float g1 = gelu_fast(acc1 * invd + b2[c0 + 1]);
  float s = g0 + g1;
  #pragma unroll
  for (int o = 32; o; o >>= 1) s += __shfl_xor(s, o);
  float mu = s * (1.f / 128.f);
  float e0 = g0 - mu, e1 = g1 - mu;
  float q = e0*e0 + e1*e1;
  #pragma unroll
  for (int o = 32; o; o >>= 1) q += __shfl_xor(q, o);
  float rstd = rsqrtf(q * (1.f / 128.f) + 1e-5f);
  float y0 = e0 * rstd * lng[c0] + lnb[c0];
  float y1 = e1 * rstd * lng[c0 + 1] + lnb[c0 + 1];
  float pr[12];
  #pragma unroll
  for (int jj = 0; jj < 8; ++jj) pr[jj] = y0 * pw[c0*8 + jj] + y1 * pw[(c0+1)*8 + jj];
  #pragma unroll
  for (int jj = 0; jj < 4; ++jj) pr[8+jj] = y0 * dwm[c0*4 + jj] + y1 * dwm[(c0+1)*4 + jj];
  #pragma unroll
  for (int o = 32; o; o >>= 1)
    #pragma unroll
    for (int jj = 0; jj < 12; ++jj) pr[jj] += __shfl_xor(pr[jj], o);
  if (lane == 0){
    #pragma unroll
    for (int jj = 0; jj < 8; ++jj) out[(size_t)n*8 + jj] = pr[jj] + pb[jj];
    #pragma unroll
    for (int jj = 0; jj < 4; ++jj) out[(size_t)NN*8 + (size_t)n*4 + jj] = pr[8+jj] + dbv[jj];
  }
}

extern "C" void kernel_launch(void* const* d_in, const int* in_sizes, int n_in,
                              void* d_out, int out_size, void* d_ws, size_t ws_size,
                              hipStream_t stream){
  const float* nf  = (const float*)d_in[0];
  const int*   ei  = (const int*)  d_in[1];
  const float* ea  = (const float*)d_in[2];
  const float* W1  = (const float*)d_in[3];
  const float* as1 = (const float*)d_in[4];
  const float* ad1 = (const float*)d_in[5];
  const float* We1 = (const float*)d_in[6];
  const float* ae1 = (const float*)d_in[7];
  const float* b1  = (const float*)d_in[8];
  const float* W2  = (const float*)d_in[9];
  const float* as2 = (const float*)d_in[10];
  const float* ad2 = (const float*)d_in[11];
  const float* We2 = (const float*)d_in[12];
  const float* ae2 = (const float*)d_in[13];
  const float* b2  = (const float*)d_in[14];
  const float* lng = (const float*)d_in[15];
  const float* lnb = (const float*)d_in[16];
  const float* pw  = (const float*)d_in[17];
  const float* pb  = (const float*)d_in[18];
  const float* dw  = (const float*)d_in[19];
  const float* db  = (const float*)d_in[20];
  float* out = (float*)d_out;

  float* wf = (float*)d_ws;
  int*      cnt  = (int*)     (wf + CNT_O);
  int*      csr  = (int*)     (wf + CSR_O);
  int*      bsum = (int*)     (wf + BSUM_O);
  int4*     epk  = (int4*)    (wf + EPK_O);
  float4*   exf1 = (float4*)  (wf + EXF1_O);
  int*      rnk  = (int*)     (wf + RNK_O);
  float*    ss1  =            (wf + SS1_O);
  float*    sd1  =            (wf + SD1_O);
  float*    ss2  =            (wf + SS2_O);
  float*    sd2  =            (wf + SD2_O);
  float*    Cc   =            (wf + CST_O);
  unsigned short* W1p = (unsigned short*)(wf + W1T_O);
  unsigned short* W2p = (unsigned short*)(wf + W2T_O);
  unsigned short* nfb = (unsigned short*)(wf + NFB_O);
  unsigned short* agg = (unsigned short*)(wf + AGG_O);
  unsigned short* xs2b= (unsigned short*)(wf + XS2_O);

  // 8 dispatches.
  k_ptw<<<TW_BLK + 1 + SCB, 256, 0, stream>>>(W1, as1, ad1, We1, ae1,
                                              W2, as2, ad2, We2, ae2,
                                              Cc, W1p, W2p, cnt);
  k_cnfs1<<<CN_BLK + DG_BLK, 256, 0, stream>>>(nf, Cc, nfb, ss1, sd1, ei, cnt, rnk);
  k_scan1<<<SCB, 256, 0, stream>>>(cnt, bsum);
  k_scan3<<<SCB, 256, 0, stream>>>(cnt, bsum, csr);
  k_fill<<<(NE + 255) / 256, 256, 0, stream>>>(ei, ea, csr, rnk, epk, ss1, sd1, Cc, exf1);
  k_aggnf<<<(NN + 3) / 4, 256, 0, stream>>>(csr, epk, exf1, nfb, ss1, sd1, Cc, agg);
  k_gemm12<<<(NN + 31) / 32, 256, 0, stream>>>(agg, W1p, W2p, b1, Cc, xs2b, ss2, sd2);
  k_agg2<<<(NN + 3) / 4, 256, 0, stream>>>(csr, epk, ss2, sd2, Cc, xs2b,
                                           b2, lng, lnb, pw, pb, dw, db, out);
}

// Round 13
// 325.520 us; speedup vs baseline: 1.0271x; 1.0271x over previous
//
#include <hip/hip_runtime.h>
#include <hip/hip_bf16.h>
#include <math.h>

#define NN 50000
#define NE 400000
#define FIN 70
#define EDIM 4
#define HIDD 128
#define NHEAD 4
constexpr int ET = NE + NN;
constexpr int KP1 = 96;           // layer-1 K padded (70 -> 96)
constexpr int NFP = 72;           // nf bf16 row pitch
constexpr int SCB = (NN + 255) / 256;   // scan blocks = 196

constexpr size_t al4(size_t x){ return (x + 3) & ~size_t(3); }
// ws offsets in 4-byte words
constexpr size_t CNT_O   = 0;                          // int[NN]
constexpr size_t ZEND    = al4(CNT_O + NN);
constexpr size_t CSR_O   = ZEND;                       // int[NN+1]
constexpr size_t BSUM_O  = al4(CSR_O + NN + 1);        // int[256]
constexpr size_t BOFF_O  = al4(BSUM_O + 256);          // int[256]
constexpr size_t EPK_O   = al4(BOFF_O + 256);          // int4[ET] {s,d,ea01,ea23}
constexpr size_t EXF1_O  = al4(EPK_O + (size_t)ET*4);  // float4[ET] exp scores L1
constexpr size_t RNK_O   = al4(EXF1_O + (size_t)ET*4); // int[NE] edge rank
constexpr size_t SS1_O   = al4(RNK_O + ET);            // f32[NN*4]
constexpr size_t SD1_O   = al4(SS1_O + (size_t)NN*4);
constexpr size_t SS2_O   = al4(SD1_O + (size_t)NN*4);  // f32[NN]
constexpr size_t SD2_O   = al4(SS2_O + NN);
constexpr size_t CST_O   = al4(SD2_O + NN);            // f32[2048]
constexpr size_t W1T_O   = al4(CST_O + 2048);          // bf16[12][128][32] panel-major
constexpr size_t W2T_O   = al4(W1T_O + 4*128*KP1/2);   // bf16[16][128][32] panel-major
constexpr size_t NFB_O   = al4(W2T_O + 128*512/2);     // bf16[NN][72]
constexpr size_t AGG_O   = al4(NFB_O + (size_t)NN*NFP/2);   // bf16[4][NN][96]
constexpr size_t XS2_O   = al4(AGG_O + (size_t)4*NN*KP1/2); // bf16[NN][128]

// const-block sub-offsets (words, within CST)
constexpr int VS1 = 0;    // [70][4]
constexpr int VD1 = 320;  // [70][4]
constexpr int VE1 = 640;  // [4][4]
constexpr int VE2 = 656;  // [4]
constexpr int VS2 = 704;  // [512]
constexpr int VD2 = 1216; // [512]

// merged-kernel block ranges
constexpr int TW_BLK = (12*128*32 + 16*128*32) / 256;  // 448 transpose blocks
constexpr int CN_BLK = (NN + 3) / 4;                   // 12500 cnfs1 blocks
constexpr int DG_BLK = (NE + 255) / 256;               // 1563 deg blocks

typedef short s8v __attribute__((ext_vector_type(8)));
typedef float f4v __attribute__((ext_vector_type(4)));

__device__ __forceinline__ unsigned short f2b(float v){
  __hip_bfloat16 b = __float2bfloat16(v);
  return *(unsigned short*)&b;
}
__device__ __forceinline__ float b2f(unsigned u_lo16){
  return __uint_as_float(u_lo16 << 16);
}
__device__ __forceinline__ unsigned pk2(float lo, float hi){
  return (unsigned)f2b(lo) | ((unsigned)f2b(hi) << 16);
}
__device__ __forceinline__ float lrelu(float x){ return x > 0.f ? x : 0.2f * x; }

// erf via A&S 7.1.26 (|err|<1.5e-7), one fast v_exp — avoids libm erff
__device__ __forceinline__ float gelu_fast(float x){
  float z = x * 0.70710678118654752440f;
  float a = fabsf(z);
  float t = 1.f / (1.f + 0.3275911f * a);
  float p = ((((1.061405429f*t - 1.453152027f)*t + 1.421413741f)*t
              - 0.284496736f)*t + 0.254829592f)*t;
  float erfv = 1.f - p * __expf(-a * a);
  erfv = copysignf(erfv, z);
  return 0.5f * x * (1.f + erfv);
}

// ---- MERGED: weight transpose + tiny pre-reductions + cnt zero --------------
// blocks [0,448): tw; block 448: prep (256 thr, 2x loop); [449,449+196): cnt=0.
__global__ void k_ptw(const float* __restrict__ W1, const float* __restrict__ as1,
                      const float* __restrict__ ad1, const float* __restrict__ We1,
                      const float* __restrict__ ae1, const float* __restrict__ W2,
                      const float* __restrict__ as2, const float* __restrict__ ad2,
                      const float* __restrict__ We2, const float* __restrict__ ae2,
                      float* __restrict__ C, unsigned short* __restrict__ W1p,
                      unsigned short* __restrict__ W2p, int* __restrict__ cnt){
  int bid = blockIdx.x, tid = threadIdx.x;
  if (bid < TW_BLK){
    int i = bid * 256 + tid;
    if (i < 12*128*32){
      int kk = i & 31, r = (i >> 5) & 127, ph = i >> 12;
      int h = ph / 3, kf = ph - 3*h;
      int kg = kf*32 + kk;
      float v = (kg < FIN) ? W1[kg*512 + h*128 + r] : 0.f;
      W1p[i] = f2b(v);
    } else {
      int j = i - 12*128*32;
      int kk = j & 31, r = (j >> 5) & 127, p = j >> 12;
      W2p[j] = f2b(W2[(p*32 + kk)*128 + r]);
    }
    return;
  }
  if (bid == TW_BLK){
    for (int t = tid; t < 512; t += 256){
      if (t < 280){
        int k = t >> 2, h = t & 3;
        float s = 0.f, d = 0.f;
        for (int dd = 0; dd < 128; ++dd){
          float w = W1[k*512 + h*128 + dd];
          s += w * as1[h*128 + dd];
          d += w * ad1[h*128 + dd];
        }
        C[VS1 + t] = s; C[VD1 + t] = d;
      }
      if (t < 16){
        int k = t >> 2, h = t & 3;
        float s = 0.f;
        for (int dd = 0; dd < 128; ++dd) s += We1[k*512 + h*128 + dd] * ae1[h*128 + dd];
        C[VE1 + t] = s;
      }
      if (t < 4){
        float s = 0.f;
        for (int dd = 0; dd < 128; ++dd) s += We2[t*128 + dd] * ae2[dd];
        C[VE2 + t] = s;
      }
      {
        float s = 0.f, d = 0.f;
        for (int dd = 0; dd < 128; ++dd){
          float w = W2[t*128 + dd];
          s += w * as2[dd];
          d += w * ad2[dd];
        }
        C[VS2 + t] = s; C[VD2 + t] = d;
      }
    }
    return;
  }
  int i = (bid - TW_BLK - 1) * 256 + tid;
  if (i < NN) cnt[i] = 0;
}

// ---- MERGED: nf -> bf16 + layer1 attn scalars  ||  degree histogram + rank --
// blocks [0,12500): cnfs1; [12500, 12500+1563): deg (rank[e] = old count).
__global__ __launch_bounds__(256) void k_cnfs1(const float* __restrict__ nf,
    const float* __restrict__ C, unsigned short* __restrict__ nfb,
    float* __restrict__ ss1, float* __restrict__ sd1,
    const int* __restrict__ ei, int* __restrict__ cnt, int* __restrict__ rnk){
  int bid = blockIdx.x;
  if (bid >= CN_BLK){
    int e = (bid - CN_BLK) * 256 + threadIdx.x;
    if (e < NE) rnk[e] = atomicAdd(&cnt[ei[NE + e]], 1);
    return;
  }
  int lane = threadIdx.x & 63, w = threadIdx.x >> 6;
  int n = bid * 4 + w;
  if (n >= NN) return;
  int c0 = lane * 2;
  bool act = lane < 35;                 // cols 0..69
  float v0 = 0.f, v1 = 0.f;
  if (act){
    v0 = nf[(size_t)n * FIN + c0];
    v1 = nf[(size_t)n * FIN + c0 + 1];
  }
  if (lane < 36) *(unsigned*)&nfb[(size_t)n * NFP + c0] = act ? pk2(v0, v1) : 0u;
  float sh[4] = {0,0,0,0}, dh[4] = {0,0,0,0};
  if (act){
    float4 cs0 = *(const float4*)&C[VS1 + c0*4];
    float4 cs1 = *(const float4*)&C[VS1 + (c0+1)*4];
    float4 cd0 = *(const float4*)&C[VD1 + c0*4];
    float4 cd1 = *(const float4*)&C[VD1 + (c0+1)*4];
    sh[0] = v0*cs0.x + v1*cs1.x; sh[1] = v0*cs0.y + v1*cs1.y;
    sh[2] = v0*cs0.z + v1*cs1.z; sh[3] = v0*cs0.w + v1*cs1.w;
    dh[0] = v0*cd0.x + v1*cd1.x; dh[1] = v0*cd0.y + v1*cd1.y;
    dh[2] = v0*cd0.z + v1*cd1.z; dh[3] = v0*cd0.w + v1*cd1.w;
  }
  #pragma unroll
  for (int o = 32; o; o >>= 1){
    #pragma unroll
    for (int h = 0; h < 4; ++h){
      sh[h] += __shfl_xor(sh[h], o);
      dh[h] += __shfl_xor(dh[h], o);
    }
  }
  if (lane == 0){
    *(float4*)&ss1[(size_t)n*4] = make_float4(sh[0], sh[1], sh[2], sh[3]);
    *(float4*)&sd1[(size_t)n*4] = make_float4(dh[0], dh[1], dh[2], dh[3]);
  }
}

// ---- CSR build: 3-phase scan of (cnt+1) -------------------------------------
__global__ void k_scan1(const int* __restrict__ cnt, int* __restrict__ bsum){
  __shared__ int ws[4];
  int t = threadIdx.x, lane = t & 63, w = t >> 6;
  int i = blockIdx.x * 256 + t;
  int v = (i < NN) ? cnt[i] + 1 : 0;
  for (int o = 32; o; o >>= 1) v += __shfl_down(v, o);
  if (lane == 0) ws[w] = v;
  __syncthreads();
  if (t == 0) bsum[blockIdx.x] = ws[0] + ws[1] + ws[2] + ws[3];
}

__global__ void k_scan2(const int* __restrict__ bsum, int* __restrict__ boff){
  __shared__ int ws[4];
  int t = threadIdx.x, lane = t & 63, w = t >> 6;
  int v = (t < SCB) ? bsum[t] : 0;
  int x = v;
  #pragma unroll
  for (int o = 1; o < 64; o <<= 1){ int u = __shfl_up(x, o); if (lane >= o) x += u; }
  if (lane == 63) ws[w] = x;
  __syncthreads();
  if (w == 0 && lane < 4){
    int y = ws[lane];
    #pragma unroll
    for (int o = 1; o < 4; o <<= 1){ int u = __shfl_up(y, o); if (lane >= o) y += u; }
    ws[lane] = y;
  }
  __syncthreads();
  int incl = x + (w > 0 ? ws[w - 1] : 0);
  if (t < SCB) boff[t] = incl - v;
}

__global__ void k_scan3(const int* __restrict__ cnt, const int* __restrict__ boff,
                        int* __restrict__ csr){
  __shared__ int ws[4];
  int t = threadIdx.x, lane = t & 63, w = t >> 6;
  int i = blockIdx.x * 256 + t;
  int v = (i < NN) ? cnt[i] + 1 : 0;
  int x = v;
  #pragma unroll
  for (int o = 1; o < 64; o <<= 1){ int u = __shfl_up(x, o); if (lane >= o) x += u; }
  if (lane == 63) ws[w] = x;
  __syncthreads();
  if (w == 0 && lane < 4){
    int y = ws[lane];
    #pragma unroll
    for (int o = 1; o < 4; o <<= 1){ int u = __shfl_up(y, o); if (lane >= o) y += u; }
    ws[lane] = y;
  }
  __syncthreads();
  if (i < NN) csr[i + 1] = boff[blockIdx.x] + (w > 0 ? ws[w - 1] : 0) + x;
  if (i == 0) csr[0] = 0;
}

// ---- fill CSR slots + FUSED layer-1 alpha (edge-parallel, ONCE per edge) ----
// p = csr[d] + rank[e] — no atomicSub; rank captured in the deg pass.
__global__ void k_fill(const int* __restrict__ ei, const float* __restrict__ ea,
                       const int* __restrict__ csr, const int* __restrict__ rnk,
                       int4* __restrict__ epk, const float* __restrict__ ss1,
                       const float* __restrict__ sd1, const float* __restrict__ C,
                       float4* __restrict__ exf){
  int e = blockIdx.x * 256 + threadIdx.x;
  if (e >= NE) return;
  int s = ei[e], d = ei[NE + e];
  int p = csr[d] + rnk[e];
  float4 a = *(const float4*)&ea[(size_t)e * 4];
  epk[p] = make_int4(s, d, (int)pk2(a.x, a.y), (int)pk2(a.z, a.w));
  float4 ssv = *(const float4*)&ss1[(size_t)s * 4];
  float4 sdv = *(const float4*)&sd1[(size_t)d * 4];
  float e0 = __expf(lrelu(ssv.x + sdv.x + a.x*C[VE1+0] + a.y*C[VE1+4] + a.z*C[VE1+8]  + a.w*C[VE1+12]));
  float e1 = __expf(lrelu(ssv.y + sdv.y + a.x*C[VE1+1] + a.y*C[VE1+5] + a.z*C[VE1+9]  + a.w*C[VE1+13]));
  float e2 = __expf(lrelu(ssv.z + sdv.z + a.x*C[VE1+2] + a.y*C[VE1+6] + a.z*C[VE1+10] + a.w*C[VE1+14]));
  float e3 = __expf(lrelu(ssv.w + sdv.w + a.x*C[VE1+3] + a.y*C[VE1+7] + a.z*C[VE1+11] + a.w*C[VE1+15]));
  exf[p] = make_float4(e0, e1, e2, e3);
}

// ---- FUSED two-stage GEMM: 2x2 wave tiling, B read ONCE per block -----------
// Converged structure (r6 config, best-measured 57.6us): each wave owns
// 32 rows x 32 cols (acc[2][2]); 4 waves split 128 cols so every B-panel byte
// is read exactly once per block. One barrier (xt handoff), 33KB LDS,
// 4 blocks/CU. Seven structural variants (r1-r5, r7, r12) all regressed or
// were neutral; this is the fixed point.
__global__ __launch_bounds__(256, 4) void k_gemm12(
    const unsigned short* __restrict__ agg, const unsigned short* __restrict__ W1p,
    const unsigned short* __restrict__ W2p, const float* __restrict__ b1,
    const float* __restrict__ Cv, unsigned short* __restrict__ xs2b,
    float* __restrict__ ss2, float* __restrict__ sd2){
  __shared__ unsigned short xt[32 * 516];   // 33.0 KB
  __shared__ float ssp[32][4], sdp[32][4];
  int tid = threadIdx.x, lane = tid & 63, wn = tid >> 6;  // wn 0..3: 32-col strip
  int m15 = lane & 15, rq = lane >> 4;
  int r0 = blockIdx.x * 32;
  int gr0 = r0 + m15;      if (gr0 >= NN) gr0 = NN - 1;
  int gr1 = r0 + 16 + m15; if (gr1 >= NN) gr1 = NN - 1;
  float s2a0 = 0.f, s2d0 = 0.f, s2a1 = 0.f, s2d1 = 0.f;
  constexpr size_t HS = (size_t)NN * KP1;
  const int bfo = (wn * 32 + m15) * 32 + rq * 8;   // +ni*512 per 16-col frag
  const unsigned short* A0 = agg + (size_t)gr0 * KP1 + rq * 8;
  const unsigned short* A1 = agg + (size_t)gr1 * KP1 + rq * 8;

  // ---------------- stage 1: 4 heads x 3 k-panels ----------------
  #pragma unroll
  for (int h = 0; h < 4; ++h){
    f4v acc[2][2] = {};
    const unsigned short* Bh = W1p + h * 3 * 4096 + bfo;
    #pragma unroll
    for (int kf = 0; kf < 3; ++kf){
      s8v a0 = *(const s8v*)(A0 + (size_t)h * HS + kf * 32);
      s8v a1 = *(const s8v*)(A1 + (size_t)h * HS + kf * 32);
      #pragma unroll
      for (int ni = 0; ni < 2; ++ni){
        s8v bf = *(const s8v*)(Bh + kf * 4096 + ni * 512);
        acc[0][ni] = __builtin_amdgcn_mfma_f32_16x16x32_bf16(bf, a0, acc[0][ni], 0, 0, 0);
        acc[1][ni] = __builtin_amdgcn_mfma_f32_16x16x32_bf16(bf, a1, acc[1][ni], 0, 0, 0);
      }
    }
    // head epilogue: gelu + xt write + ss2/sd2 register accumulation (2 rows)
    #pragma unroll
    for (int m = 0; m < 2; ++m){
      #pragma unroll
      for (int ni = 0; ni < 2; ++ni){
        int cb = h * 128 + wn * 32 + ni * 16 + rq * 4;
        float4 bv = *(const float4*)&b1[cb];
        float v0 = gelu_fast(acc[m][ni][0] + bv.x);
        float v1 = gelu_fast(acc[m][ni][1] + bv.y);
        float v2 = gelu_fast(acc[m][ni][2] + bv.z);
        float v3 = gelu_fast(acc[m][ni][3] + bv.w);
        float4 cs = *(const float4*)&Cv[VS2 + cb];
        float4 cd = *(const float4*)&Cv[VD2 + cb];
        float pa = v0*cs.x + v1*cs.y + v2*cs.z + v3*cs.w;
        float pd = v0*cd.x + v1*cd.y + v2*cd.z + v3*cd.w;
        if (m == 0){ s2a0 += pa; s2d0 += pd; } else { s2a1 += pa; s2d1 += pd; }
        *(uint2*)&xt[(m * 16 + m15) * 516 + cb] = make_uint2(pk2(v0, v1), pk2(v2, v3));
      }
    }
  }
  // ss2/sd2: reduce over rq lanes, park per-wave partials in tiny LDS
  s2a0 += __shfl_xor(s2a0, 16); s2a0 += __shfl_xor(s2a0, 32);
  s2d0 += __shfl_xor(s2d0, 16); s2d0 += __shfl_xor(s2d0, 32);
  s2a1 += __shfl_xor(s2a1, 16); s2a1 += __shfl_xor(s2a1, 32);
  s2d1 += __shfl_xor(s2d1, 16); s2d1 += __shfl_xor(s2d1, 32);
  if (rq == 0){
    ssp[m15][wn] = s2a0;      sdp[m15][wn] = s2d0;
    ssp[16 + m15][wn] = s2a1; sdp[16 + m15][wn] = s2d1;
  }

  __syncthreads();                          // the ONLY barrier

  if (tid < 32 && r0 + tid < NN){
    ss2[r0 + tid] = (ssp[tid][0] + ssp[tid][1]) + (ssp[tid][2] + ssp[tid][3]);
    sd2[r0 + tid] = (sdp[tid][0] + sdp[tid][1]) + (sdp[tid][2] + sdp[tid][3]);
  }

  // ---------------- stage 2: 16 k-panels ----------------
  f4v acc2[2][2] = {};
  #pragma unroll
  for (int p = 0; p < 16; ++p){
    s8v x0 = *(const s8v*)&xt[m15 * 516 + p * 32 + rq * 8];
    s8v x1 = *(const s8v*)&xt[(16 + m15) * 516 + p * 32 + rq * 8];
    #pragma unroll
    for (int ni = 0; ni < 2; ++ni){
      s8v bf = *(const s8v*)(W2p + p * 4096 + bfo + ni * 512);
      acc2[0][ni] = __builtin_amdgcn_mfma_f32_16x16x32_bf16(bf, x0, acc2[0][ni], 0, 0, 0);
      acc2[1][ni] = __builtin_amdgcn_mfma_f32_16x16x32_bf16(bf, x1, acc2[1][ni], 0, 0, 0);
    }
  }
  #pragma unroll
  for (int m = 0; m < 2; ++m){
    int grow = r0 + m * 16 + m15;
    if (grow < NN){
      #pragma unroll
      for (int ni = 0; ni < 2; ++ni){
        int gc = wn * 32 + ni * 16 + rq * 4;
        *(uint2*)&xs2b[(size_t)grow * 128 + gc] =
            make_uint2(pk2(acc2[m][ni][0], acc2[m][ni][1]),
                       pk2(acc2[m][ni][2], acc2[m][ni][3]));
      }
    }
  }
}

// ---- layer1 aggregation (reads exf) + FUSED self-loop, 4-wide edge unroll ---
__global__ __launch_bounds__(256) void k_aggnf(const int* __restrict__ csr,
    int4* __restrict__ epk, const float4* __restrict__ exf,
    const unsigned short* __restrict__ nfb, const float* __restrict__ ss1,
    const float* __restrict__ sd1, const float* __restrict__ Cv,
    unsigned short* __restrict__ agg){
  int lane = threadIdx.x & 63, w = threadIdx.x >> 6;
  int n = blockIdx.x * 4 + w;
  if (n >= NN) return;
  int off = __builtin_amdgcn_readfirstlane(csr[n]);
  int end = __builtin_amdgcn_readfirstlane(csr[n + 1]);
  int endr = end - 1;                   // real edges in [off, endr)
  int col = lane * 2;
  bool act = lane < 36;
  float d0=0,d1=0,d2=0,d3=0;
  float a00=0,a01=0,a10=0,a11=0,a20=0,a21=0,a30=0,a31=0;
  float t0=0,t1=0,t2=0,t3=0;            // attr sums for self-loop mean
  int p = off;
  for (; p + 4 <= endr; p += 4){
    int4 q0 = epk[p], q1 = epk[p+1], q2 = epk[p+2], q3 = epk[p+3];
    float4 e0 = exf[p], e1 = exf[p+1], e2 = exf[p+2], e3 = exf[p+3];
    unsigned u0 = 0, u1 = 0, u2 = 0, u3 = 0;
    if (act){
      u0 = *(const unsigned*)&nfb[(size_t)q0.x * NFP + col];
      u1 = *(const unsigned*)&nfb[(size_t)q1.x * NFP + col];
      u2 = *(const unsigned*)&nfb[(size_t)q2.x * NFP + col];
      u3 = *(const unsigned*)&nfb[(size_t)q3.x * NFP + col];
    }
    t0 += (b2f((unsigned)q0.z & 0xffffu) + b2f((unsigned)q1.z & 0xffffu))
        + (b2f((unsigned)q2.z & 0xffffu) + b2f((unsigned)q3.z & 0xffffu));
    t1 += (b2f((unsigned)q0.z >> 16) + b2f((unsigned)q1.z >> 16))
        + (b2f((unsigned)q2.z >> 16) + b2f((unsigned)q3.z >> 16));
    t2 += (b2f((unsigned)q0.w & 0xffffu) + b2f((unsigned)q1.w & 0xffffu))
        + (b2f((unsigned)q2.w & 0xffffu) + b2f((unsigned)q3.w & 0xffffu));
    t3 += (b2f((unsigned)q0.w >> 16) + b2f((unsigned)q1.w >> 16))
        + (b2f((unsigned)q2.w >> 16) + b2f((unsigned)q3.w >> 16));
    d0 += (e0.x + e1.x) + (e2.x + e3.x);
    d1 += (e0.y + e1.y) + (e2.y + e3.y);
    d2 += (e0.z + e1.z) + (e2.z + e3.z);
    d3 += (e0.w + e1.w) + (e2.w + e3.w);
    float v00 = b2f(u0 & 0xffffu), v01 = b2f(u0 >> 16);
    float v10 = b2f(u1 & 0xffffu), v11 = b2f(u1 >> 16);
    float v20 = b2f(u2 & 0xffffu), v21 = b2f(u2 >> 16);
    float v30 = b2f(u3 & 0xffffu), v31 = b2f(u3 >> 16);
    a00 += (e0.x*v00 + e1.x*v10) + (e2.x*v20 + e3.x*v30);
    a01 += (e0.x*v01 + e1.x*v11) + (e2.x*v21 + e3.x*v31);
    a10 += (e0.y*v00 + e1.y*v10) + (e2.y*v20 + e3.y*v30);
    a11 += (e0.y*v01 + e1.y*v11) + (e2.y*v21 + e3.y*v31);
    a20 += (e0.z*v00 + e1.z*v10) + (e2.z*v20 + e3.z*v30);
    a21 += (e0.z*v01 + e1.z*v11) + (e2.z*v21 + e3.z*v31);
    a30 += (e0.w*v00 + e1.w*v10) + (e2.w*v20 + e3.w*v30);
    a31 += (e0.w*v01 + e1.w*v11) + (e2.w*v21 + e3.w*v31);
  }
  for (; p + 2 <= endr; p += 2){
    int4 q0 = epk[p], q1 = epk[p+1];
    float4 e0 = exf[p], e1 = exf[p+1];
    unsigned u0 = 0, u1 = 0;
    if (act){
      u0 = *(const unsigned*)&nfb[(size_t)q0.x * NFP + col];
      u1 = *(const unsigned*)&nfb[(size_t)q1.x * NFP + col];
    }
    t0 += b2f((unsigned)q0.z & 0xffffu) + b2f((unsigned)q1.z & 0xffffu);
    t1 += b2f((unsigned)q0.z >> 16)     + b2f((unsigned)q1.z >> 16);
    t2 += b2f((unsigned)q0.w & 0xffffu) + b2f((unsigned)q1.w & 0xffffu);
    t3 += b2f((unsigned)q0.w >> 16)     + b2f((unsigned)q1.w >> 16);
    d0 += e0.x + e1.x; d1 += e0.y + e1.y; d2 += e0.z + e1.z; d3 += e0.w + e1.w;
    float v00 = b2f(u0 & 0xffffu), v01 = b2f(u0 >> 16);
    float v10 = b2f(u1 & 0xffffu), v11 = b2f(u1 >> 16);
    a00 += e0.x*v00 + e1.x*v10; a01 += e0.x*v01 + e1.x*v11;
    a10 += e0.y*v00 + e1.y*v10; a11 += e0.y*v01 + e1.y*v11;
    a20 += e0.z*v00 + e1.z*v10; a21 += e0.z*v01 + e1.z*v11;
    a30 += e0.w*v00 + e1.w*v10; a31 += e0.w*v01 + e1.w*v11;
  }
  if (p < endr){
    int4 q0 = epk[p];
    float4 e0 = exf[p];
    unsigned u0 = 0;
    if (act) u0 = *(const unsigned*)&nfb[(size_t)q0.x * NFP + col];
    t0 += b2f((unsigned)q0.z & 0xffffu); t1 += b2f((unsigned)q0.z >> 16);
    t2 += b2f((unsigned)q0.w & 0xffffu); t3 += b2f((unsigned)q0.w >> 16);
    d0 += e0.x; d1 += e0.y; d2 += e0.z; d3 += e0.w;
    float v00 = b2f(u0 & 0xffffu), v01 = b2f(u0 >> 16);
    a00 += e0.x*v00; a01 += e0.x*v01;
    a10 += e0.y*v00; a11 += e0.y*v01;
    a20 += e0.z*v00; a21 += e0.z*v01;
    a30 += e0.w*v00; a31 += e0.w*v01;
  }
  // ---- self loop: mean attrs (bf16-rounded like k_fill), alpha, contribution
  int deg = endr - off;
  float inv = 1.f / (float)(deg > 1 ? deg : 1);
  float m0 = t0*inv, m1 = t1*inv, m2 = t2*inv, m3 = t3*inv;
  if (lane == 0) epk[endr] = make_int4(n, n, (int)pk2(m0, m1), (int)pk2(m2, m3));
  float4 ssv = *(const float4*)&ss1[(size_t)n * 4];
  float4 sdn = *(const float4*)&sd1[(size_t)n * 4];
  float e0 = __expf(lrelu(ssv.x + sdn.x + m0*Cv[VE1+0] + m1*Cv[VE1+4] + m2*Cv[VE1+8]  + m3*Cv[VE1+12]));
  float e1 = __expf(lrelu(ssv.y + sdn.y + m0*Cv[VE1+1] + m1*Cv[VE1+5] + m2*Cv[VE1+9]  + m3*Cv[VE1+13]));
  float e2 = __expf(lrelu(ssv.z + sdn.z + m0*Cv[VE1+2] + m1*Cv[VE1+6] + m2*Cv[VE1+10] + m3*Cv[VE1+14]));
  float e3 = __expf(lrelu(ssv.w + sdn.w + m0*Cv[VE1+3] + m1*Cv[VE1+7] + m2*Cv[VE1+11] + m3*Cv[VE1+15]));
  {
    unsigned us = act ? *(const unsigned*)&nfb[(size_t)n * NFP + col] : 0u;
    float v0 = b2f(us & 0xffffu), v1 = b2f(us >> 16);
    d0 += e0; d1 += e1; d2 += e2; d3 += e3;
    a00 += e0*v0; a01 += e0*v1;
    a10 += e1*v0; a11 += e1*v1;
    a20 += e2*v0; a21 += e2*v1;
    a30 += e3*v0; a31 += e3*v1;
  }
  float i0 = 1.f/(d0+1e-16f), i1 = 1.f/(d1+1e-16f);
  float i2 = 1.f/(d2+1e-16f), i3 = 1.f/(d3+1e-16f);
  constexpr size_t HS = (size_t)NN * KP1;
  size_t base = (size_t)n * KP1 + col;
  if (act){
    *(unsigned*)&agg[base]        = pk2(a00*i0, a01*i0);
    *(unsigned*)&agg[base +   HS] = pk2(a10*i1, a11*i1);
    *(unsigned*)&agg[base + 2*HS] = pk2(a20*i2, a21*i2);
    *(unsigned*)&agg[base + 3*HS] = pk2(a30*i3, a31*i3);
  } else if (lane < 48){                // zero cols 72..95
    *(unsigned*)&agg[base]        = 0u;
    *(unsigned*)&agg[base +   HS] = 0u;
    *(unsigned*)&agg[base + 2*HS] = 0u;
    *(unsigned*)&agg[base + 3*HS] = 0u;
  }
}

// ---- layer2 aggregation + FUSED alpha + GELU + LN + projections -------------
__global__ __launch_bounds__(256) void k_agg2(
    const int* __restrict__ csr, const int4* __restrict__ epk,
    const float* __restrict__ ss2, const float* __restrict__ sd2,
    const float* __restrict__ Cv, const unsigned short* __restrict__ xs2b,
    const float* __restrict__ b2, const float* __restrict__ lng,
    const float* __restrict__ lnb, const float* __restrict__ pw,
    const float* __restrict__ pb, const float* __restrict__ dwm,
    const float* __restrict__ dbv, float* __restrict__ out){
  int lane = threadIdx.x & 63, w = threadIdx.x >> 6;
  int n = blockIdx.x * 4 + w;
  if (n >= NN) return;
  int off = __builtin_amdgcn_readfirstlane(csr[n]);
  int end = __builtin_amdgcn_readfirstlane(csr[n + 1]);
  float sd2n = sd2[n];
  float cv0 = Cv[VE2], cv1 = Cv[VE2+1], cv2 = Cv[VE2+2], cv3 = Cv[VE2+3];
  int c0 = lane * 2;
  float acc0 = 0.f, acc1 = 0.f, den = 0.f;
  int p = off;
  for (; p + 4 <= end; p += 4){
    int4 p0 = epk[p], p1 = epk[p+1], p2 = epk[p+2], p3 = epk[p+3];
    int s0 = p0.x, s1 = p1.x, s2 = p2.x, s3 = p3.x;
    float sv0 = ss2[s0], sv1 = ss2[s1], sv2 = ss2[s2], sv3 = ss2[s3];
    unsigned u0 = *(const unsigned*)&xs2b[(size_t)s0 * 128 + c0];
    unsigned u1 = *(const unsigned*)&xs2b[(size_t)s1 * 128 + c0];
    unsigned u2 = *(const unsigned*)&xs2b[(size_t)s2 * 128 + c0];
    unsigned u3 = *(const unsigned*)&xs2b[(size_t)s3 * 128 + c0];
    float e0 = __expf(lrelu(sv0 + sd2n
             + b2f((unsigned)p0.z & 0xffffu)*cv0 + b2f((unsigned)p0.z >> 16)*cv1
             + b2f((unsigned)p0.w & 0xffffu)*cv2 + b2f((unsigned)p0.w >> 16)*cv3));
    float e1 = __expf(lrelu(sv1 + sd2n
             + b2f((unsigned)p1.z & 0xffffu)*cv0 + b2f((unsigned)p1.z >> 16)*cv1
             + b2f((unsigned)p1.w & 0xffffu)*cv2 + b2f((unsigned)p1.w >> 16)*cv3));
    float e2 = __expf(lrelu(sv2 + sd2n
             + b2f((unsigned)p2.z & 0xffffu)*cv0 + b2f((unsigned)p2.z >> 16)*cv1
             + b2f((unsigned)p2.w & 0xffffu)*cv2 + b2f((unsigned)p2.w >> 16)*cv3));
    float e3 = __expf(lrelu(sv3 + sd2n
             + b2f((unsigned)p3.z & 0xffffu)*cv0 + b2f((unsigned)p3.z >> 16)*cv1
             + b2f((unsigned)p3.w & 0xffffu)*cv2 + b2f((unsigned)p3.w >> 16)*cv3));
    den += (e0 + e1) + (e2 + e3);
    acc0 += (e0*b2f(u0 & 0xffffu) + e1*b2f(u1 & 0xffffu))
          + (e2*b2f(u2 & 0xffffu) + e3*b2f(u3 & 0xffffu));
    acc1 += (e0*b2f(u0 >> 16) + e1*b2f(u1 >> 16))
          + (e2*b2f(u2 >> 16) + e3*b2f(u3 >> 16));
  }
  for (; p + 2 <= end; p += 2){
    int4 p0 = epk[p], p1 = epk[p+1];
    int s0 = p0.x, s1 = p1.x;
    float sv0 = ss2[s0], sv1 = ss2[s1];
    unsigned u0 = *(const unsigned*)&xs2b[(size_t)s0 * 128 + c0];
    unsigned u1 = *(const unsigned*)&xs2b[(size_t)s1 * 128 + c0];
    float e0 = __expf(lrelu(sv0 + sd2n
             + b2f((unsigned)p0.z & 0xffffu)*cv0 + b2f((unsigned)p0.z >> 16)*cv1
             + b2f((unsigned)p0.w & 0xffffu)*cv2 + b2f((unsigned)p0.w >> 16)*cv3));
    float e1 = __expf(lrelu(sv1 + sd2n
             + b2f((unsigned)p1.z & 0xffffu)*cv0 + b2f((unsigned)p1.z >> 16)*cv1
             + b2f((unsigned)p1.w & 0xffffu)*cv2 + b2f((unsigned)p1.w >> 16)*cv3));
    den += e0 + e1;
    acc0 += e0*b2f(u0 & 0xffffu) + e1*b2f(u1 & 0xffffu);
    acc1 += e0*b2f(u0 >> 16) + e1*b2f(u1 >> 16);
  }
  if (p < end){
    int4 p0 = epk[p];
    int s0 = p0.x;
    float sv0 = ss2[s0];
    unsigned u0 = *(const unsigned*)&xs2b[(size_t)s0 * 128 + c0];
    float e0 = __expf(lrelu(sv0 + sd2n
             + b2f((unsigned)p0.z & 0xffffu)*cv0 + b2f((unsigned)p0.z >> 16)*cv1
             + b2f((unsigned)p0.w & 0xffffu)*cv2 + b2f((unsigned)p0.w >> 16)*cv3));
    den += e0;
    acc0 += e0*b2f(u0 & 0xffffu);
    acc1 += e0*b2f(u0 >> 16);
  }
  float invd = 1.f / (den + 1e-16f);
  float g0 = gelu_fast(acc0 * invd + b2[c0]);
  float g1 = gelu_fast(acc1 * invd + b2[c0 + 1]);
  float s = g0 + g1;
  #pragma unroll
  for (int o = 32; o; o >>= 1) s += __shfl_xor(s, o);
  float mu = s * (1.f / 128.f);
  float e0 = g0 - mu, e1 = g1 - mu;
  float q = e0*e0 + e1*e1;
  #pragma unroll
  for (int o = 32; o; o >>= 1) q += __shfl_xor(q, o);
  float rstd = rsqrtf(q * (1.f / 128.f) + 1e-5f);
  float y0 = e0 * rstd * lng[c0] + lnb[c0];
  float y1 = e1 * rstd * lng[c0 + 1] + lnb[c0 + 1];
  float pr[12];
  #pragma unroll
  for (int jj = 0; jj < 8; ++jj) pr[jj] = y0 * pw[c0*8 + jj] + y1 * pw[(c0+1)*8 + jj];
  #pragma unroll
  for (int jj = 0; jj < 4; ++jj) pr[8+jj] = y0 * dwm[c0*4 + jj] + y1 * dwm[(c0+1)*4 + jj];
  #pragma unroll
  for (int o = 32; o; o >>= 1)
    #pragma unroll
    for (int jj = 0; jj < 12; ++jj) pr[jj] += __shfl_xor(pr[jj], o);
  if (lane == 0){
    #pragma unroll
    for (int jj = 0; jj < 8; ++jj) out[(size_t)n*8 + jj] = pr[jj] + pb[jj];
    #pragma unroll
    for (int jj = 0; jj < 4; ++jj) out[(size_t)NN*8 + (size_t)n*4 + jj] = pr[8+jj] + dbv[jj];
  }
}

extern "C" void kernel_launch(void* const* d_in, const int* in_sizes, int n_in,
                              void* d_out, int out_size, void* d_ws, size_t ws_size,
                              hipStream_t stream){
  const float* nf  = (const float*)d_in[0];
  const int*   ei  = (const int*)  d_in[1];
  const float* ea  = (const float*)d_in[2];
  const float* W1  = (const float*)d_in[3];
  const float* as1 = (const float*)d_in[4];
  const float* ad1 = (const float*)d_in[5];
  const float* We1 = (const float*)d_in[6];
  const float* ae1 = (const float*)d_in[7];
  const float* b1  = (const float*)d_in[8];
  const float* W2  = (const float*)d_in[9];
  const float* as2 = (const float*)d_in[10];
  const float* ad2 = (const float*)d_in[11];
  const float* We2 = (const float*)d_in[12];
  const float* ae2 = (const float*)d_in[13];
  const float* b2  = (const float*)d_in[14];
  const float* lng = (const float*)d_in[15];
  const float* lnb = (const float*)d_in[16];
  const float* pw  = (const float*)d_in[17];
  const float* pb  = (const float*)d_in[18];
  const float* dw  = (const float*)d_in[19];
  const float* db  = (const float*)d_in[20];
  float* out = (float*)d_out;

  float* wf = (float*)d_ws;
  int*      cnt  = (int*)     (wf + CNT_O);
  int*      csr  = (int*)     (wf + CSR_O);
  int*      bsum = (int*)     (wf + BSUM_O);
  int*      boff = (int*)     (wf + BOFF_O);
  int4*     epk  = (int4*)    (wf + EPK_O);
  float4*   exf1 = (float4*)  (wf + EXF1_O);
  int*      rnk  = (int*)     (wf + RNK_O);
  float*    ss1  =            (wf + SS1_O);
  float*    sd1  =            (wf + SD1_O);
  float*    ss2  =            (wf + SS2_O);
  float*    sd2  =            (wf + SD2_O);
  float*    Cc   =            (wf + CST_O);
  unsigned short* W1p = (unsigned short*)(wf + W1T_O);
  unsigned short* W2p = (unsigned short*)(wf + W2T_O);
  unsigned short* nfb = (unsigned short*)(wf + NFB_O);
  unsigned short* agg = (unsigned short*)(wf + AGG_O);
  unsigned short* xs2b= (unsigned short*)(wf + XS2_O);

  // 9 dispatches: ptw merges prep+tw+memset; cnfs1 merges deg(+rank).
  k_ptw<<<TW_BLK + 1 + SCB, 256, 0, stream>>>(W1, as1, ad1, We1, ae1,
                                              W2, as2, ad2, We2, ae2,
                                              Cc, W1p, W2p, cnt);
  k_cnfs1<<<CN_BLK + DG_BLK, 256, 0, stream>>>(nf, Cc, nfb, ss1, sd1, ei, cnt, rnk);
  k_scan1<<<SCB, 256, 0, stream>>>(cnt, bsum);
  k_scan2<<<1, 256, 0, stream>>>(bsum, boff);
  k_scan3<<<SCB, 256, 0, stream>>>(cnt, boff, csr);
  k_fill<<<(NE + 255) / 256, 256, 0, stream>>>(ei, ea, csr, rnk, epk, ss1, sd1, Cc, exf1);
  k_aggnf<<<(NN + 3) / 4, 256, 0, stream>>>(csr, epk, exf1, nfb, ss1, sd1, Cc, agg);
  k_gemm12<<<(NN + 31) / 32, 256, 0, stream>>>(agg, W1p, W2p, b1, Cc, xs2b, ss2, sd2);
  k_agg2<<<(NN + 3) / 4, 256, 0, stream>>>(csr, epk, ss2, sd2, Cc, xs2b,
                                           b2, lng, lnb, pw, pb, dw, db, out);
}